// Round 5
// baseline (585.223 us; speedup 1.0000x reference)
//
#include <hip/hip_runtime.h>
#include <math.h>

// Problem constants
#define HH 2048
#define EE 64
#define TOPK 8
#define NT 16384
#define TW 16            // tokens per wave (gemm)
#define BT 64            // tokens per WG (reduce kernel)
#define LS 68            // slog row stride (floats) in reduce kernel

// ---------------- Kernel 0: transpose w [E][H] -> wt[H/4][E][4] ----------------
// wt[(k>>2)*EE*4 + e*4 + (k&3)] = w[e][k]. 512 KB, runs once per call (~2 us).
__global__ __launch_bounds__(256, 1) void wtrans(
    const float* __restrict__ w, float* __restrict__ wt)
{
    const int id = blockIdx.x * 256 + threadIdx.x;   // 0..32767 = (e, kq)
    const int e  = id >> 9;                          // 0..63
    const int kq = id & 511;                         // consecutive lanes -> coalesced read
    float4 v = *(const float4*)(w + (size_t)e * HH + (kq << 2));
    *(float4*)(wt + ((size_t)kq * EE + e) * 4) = v;
}

// ---------------- Kernel 1: lane-per-expert fp32 GEMM partial ----------------
// One wave per block. lane = expert. acc[t] = logit[tok0+t][lane] over K-range.
// x loads are wave-uniform (no threadIdx in address) -> scalar/broadcast;
// w loads coalesced via wt. No LDS, no barriers. K ascending per acc ->
// bitwise-identical partials to round 4 (validated numerics).
__global__ __launch_bounds__(64, 4) void gemm_lane(
    const float* __restrict__ x,    // [NT, H]
    const float* __restrict__ wt,   // [H/4][E][4]
    float* __restrict__ P,          // [S][NT, E]
    int kper)
{
    const int e    = threadIdx.x;          // lane = expert
    const int tok0 = blockIdx.x * TW;
    const int s    = blockIdx.y;
    const int kq0  = (s * kper) >> 2;      // starting k-quad
    const int nq   = kper >> 2;            // quads in this K-range

    float acc[TW];
#pragma unroll
    for (int t = 0; t < TW; ++t) acc[t] = 0.f;

    const float* wp = wt + ((size_t)kq0 * EE + e) * 4;
    const float* xp = x + (size_t)tok0 * HH + (kq0 << 2);

    float4 wv = *(const float4*)wp;
    for (int q = 0; q < nq; ++q) {
        float4 wn;
        if (q + 1 < nq) wn = *(const float4*)(wp + (size_t)(q + 1) * EE * 4);

        const float* xq = xp + (q << 2);
#pragma unroll
        for (int t = 0; t < TW; ++t) {
            float4 xv = *(const float4*)(xq + (size_t)t * HH);   // uniform address
            acc[t] = fmaf(xv.x, wv.x, acc[t]);
            acc[t] = fmaf(xv.y, wv.y, acc[t]);
            acc[t] = fmaf(xv.z, wv.z, acc[t]);
            acc[t] = fmaf(xv.w, wv.w, acc[t]);
        }
        wv = wn;
    }

    // write partials: P[s][tok0+t][e] (lane-consecutive -> coalesced 256B rows)
    float* Pp = P + ((size_t)s * NT + tok0) * EE + e;
#pragma unroll
    for (int t = 0; t < TW; ++t) Pp[(size_t)t * EE] = acc[t];
}

// ---------------- Kernel 2: reduce S slices + logits + top-8 softmax ----------------
// (verbatim from round 4 — proven correct)
__global__ __launch_bounds__(256, 1) void reduce_topk(
    const float* __restrict__ P,   // [S][NT, E]
    int S,
    float* __restrict__ out_logits,
    float* __restrict__ out_wts,
    float* __restrict__ out_idx)
{
    __shared__ float slog[BT * LS];

    const int t    = threadIdx.x;
    const int tok0 = blockIdx.x * BT;
    const int tr   = t >> 2;        // token row 0..63
    const int p    = t & 3;         // expert 16-block

    float v[16];
#pragma unroll
    for (int c = 0; c < 4; ++c) {
        float4 a = *(const float4*)(P + ((size_t)(tok0 + tr)) * EE + 16 * p + 4 * c);
        v[4 * c + 0] = a.x; v[4 * c + 1] = a.y; v[4 * c + 2] = a.z; v[4 * c + 3] = a.w;
    }
    for (int s = 1; s < S; ++s) {
#pragma unroll
        for (int c = 0; c < 4; ++c) {
            float4 a = *(const float4*)(P + ((size_t)s * NT + tok0 + tr) * EE + 16 * p + 4 * c);
            v[4 * c + 0] += a.x; v[4 * c + 1] += a.y; v[4 * c + 2] += a.z; v[4 * c + 3] += a.w;
        }
    }

    // store logits + stage for top-k
#pragma unroll
    for (int c = 0; c < 4; ++c) {
        float4 a;
        a.x = v[4 * c + 0]; a.y = v[4 * c + 1]; a.z = v[4 * c + 2]; a.w = v[4 * c + 3];
        *(float4*)(out_logits + (size_t)(tok0 + tr) * EE + 16 * p + 4 * c) = a;
        *(float4*)&slog[tr * LS + 16 * p + 4 * c] = a;
    }
    __syncthreads();

    // ---- top-8 + softmax: one lane per token ----
    if (t < BT) {
        float tv[TOPK];
        int   ti[TOPK];
#pragma unroll
        for (int q = 0; q < TOPK; ++q) { tv[q] = -INFINITY; ti[q] = 0; }

        for (int e = 0; e < EE; ++e) {
            const float val = slog[t * LS + e];
            if (val > tv[TOPK - 1]) {
                tv[TOPK - 1] = val;
                ti[TOPK - 1] = e;
#pragma unroll
                for (int q = TOPK - 1; q > 0; --q) {
                    if (tv[q] > tv[q - 1]) {   // strict: lowest-index-first on ties
                        float fv = tv[q]; tv[q] = tv[q - 1]; tv[q - 1] = fv;
                        int   fi = ti[q]; ti[q] = ti[q - 1]; ti[q - 1] = fi;
                    }
                }
            }
        }

        const float m = tv[0];
        float ew[TOPK];
        float sum = 0.f;
#pragma unroll
        for (int q = 0; q < TOPK; ++q) { ew[q] = expf(tv[q] - m); sum += ew[q]; }
        const float inv = 1.f / sum;

        const size_t tok = (size_t)(tok0 + t);
        float4 w0, w1, i0, i1;
        w0.x = ew[0] * inv; w0.y = ew[1] * inv; w0.z = ew[2] * inv; w0.w = ew[3] * inv;
        w1.x = ew[4] * inv; w1.y = ew[5] * inv; w1.z = ew[6] * inv; w1.w = ew[7] * inv;
        i0.x = (float)ti[0]; i0.y = (float)ti[1]; i0.z = (float)ti[2]; i0.w = (float)ti[3];
        i1.x = (float)ti[4]; i1.y = (float)ti[5]; i1.z = (float)ti[6]; i1.w = (float)ti[7];
        *(float4*)(out_wts + tok * TOPK)     = w0;
        *(float4*)(out_wts + tok * TOPK + 4) = w1;
        *(float4*)(out_idx + tok * TOPK)     = i0;
        *(float4*)(out_idx + tok * TOPK + 4) = i1;
    }
}

extern "C" void kernel_launch(void* const* d_in, const int* in_sizes, int n_in,
                              void* d_out, int out_size, void* d_ws, size_t ws_size,
                              hipStream_t stream) {
    const float* x = (const float*)d_in[0];   // hidden_states [4,4096,2048] fp32
    const float* w = (const float*)d_in[1];   // gate_w [64,2048] fp32
    float* out        = (float*)d_out;
    float* out_logits = out;                              // 16384*64
    float* out_wts    = out + (size_t)NT * EE;            // 16384*8
    float* out_idx    = out_wts + (size_t)NT * TOPK;      // 16384*8

    const size_t wtB    = (size_t)EE * HH * sizeof(float);      // 512 KB
    const size_t sliceB = (size_t)NT * EE * sizeof(float);      // 4.19 MB per slice

    float* wt = (float*)d_ws;                 // transposed w at ws start
    float* Pbase = (float*)((char*)d_ws + wtB);

    int S;
    float* P;
    if (ws_size >= wtB + 4 * sliceB)      { S = 4; P = Pbase; }
    else if (ws_size >= wtB + 2 * sliceB) { S = 2; P = Pbase; }
    else                                  { S = 1; P = out_logits; }

    // 0) transpose w
    hipLaunchKernelGGL(wtrans, dim3(128), dim3(256), 0, stream, w, wt);

    // 1) lane-per-expert GEMM partials
    dim3 grid1(NT / TW, S), block1(64);
    hipLaunchKernelGGL(gemm_lane, grid1, block1, 0, stream, x, wt, P, HH / S);

    // 2) reduce + top-k + softmax
    dim3 grid2(NT / BT), block2(256);
    hipLaunchKernelGGL(reduce_topk, grid2, block2, 0, stream,
                       P, S, out_logits, out_wts, out_idx);
}

// Round 6
// 427.992 us; speedup vs baseline: 1.3674x; 1.3674x over previous
//
#include <hip/hip_runtime.h>
#include <math.h>

// Problem constants
#define HH 2048
#define EE 64
#define TOPK 8
#define NT 16384
#define KC 32            // K per chunk
#define XS 33            // x LDS row stride (floats): banks (l+kk)%32 -> 2-way max (free)
#define BT 32            // tokens per WG in reduce kernel
#define LS 68            // slog row stride in reduce kernel

// ---------------- Kernel 1: fp32 GEMM partial, lane=token / wave=16 experts ----------------
// grid (256, S); block 256 = 4 waves. Token tile 64 (lane = token), wave wv owns
// experts wv*16..+16 (wave-uniform -> readfirstlane -> w loads go scalar, L2-hot).
// Per chunk: stage x[64][32] -> LDS (coalesced), each lane pulls its token row into
// xr[32] regs ONCE, then 16 experts x 32 k FMAs reuse it (512 FMA : 32 ds_read).
// K ascending per accumulator -> bitwise-identical partials to rounds 4/5.
__global__ __launch_bounds__(256, 1) void gemm_xr(
    const float* __restrict__ x,   // [NT, H]
    const float* __restrict__ w,   // [E, H]
    float* __restrict__ P,         // [S][NT, E]
    int kper)
{
    __shared__ float sx[2][64 * XS];

    const int t  = threadIdx.x;
    const int l  = t & 63;                    // lane = token within tile
    const int wv = t >> 6;                    // wave 0..3
    const int e0 = __builtin_amdgcn_readfirstlane(wv * 16);  // uniform expert base
    const int tok0 = blockIdx.x * 64;
    const int s    = blockIdx.y;
    const int k0   = s * kper;
    const int nch  = kper / KC;               // 16

    // staging: float4 index v = t and t+256; row = v>>3 (0..63), col = (v&7)*4
    const int srow = t >> 3;                  // 0..31 (second half via +32)
    const int scol = (t & 7) * 4;

    float acc[16];
#pragma unroll
    for (int j = 0; j < 16; ++j) acc[j] = 0.f;

    float4 p0, p1;

    // ---- prologue: chunk 0 ----
    p0 = *(const float4*)(x + (size_t)(tok0 + srow) * HH + k0 + scol);
    p1 = *(const float4*)(x + (size_t)(tok0 + srow + 32) * HH + k0 + scol);
    {
        float* d0 = &sx[0][srow * XS + scol];
        float* d1 = &sx[0][(srow + 32) * XS + scol];
        d0[0] = p0.x; d0[1] = p0.y; d0[2] = p0.z; d0[3] = p0.w;
        d1[0] = p1.x; d1[1] = p1.y; d1[2] = p1.z; d1[3] = p1.w;
    }
    __syncthreads();

    const float* wbase = w + (size_t)e0 * HH + k0;

    for (int c = 0; c < nch; ++c) {
        const int buf = c & 1;
        const bool more = (c + 1 < nch);
        if (more) {
            const int kn = k0 + (c + 1) * KC;
            p0 = *(const float4*)(x + (size_t)(tok0 + srow) * HH + kn + scol);
            p1 = *(const float4*)(x + (size_t)(tok0 + srow + 32) * HH + kn + scol);
        }

        // pull my token's K-chunk into registers (reused by all 16 experts)
        float xr[KC];
#pragma unroll
        for (int kk = 0; kk < KC; ++kk) xr[kk] = sx[buf][l * XS + kk];

        // expert loop, software-pipelined w rows (scalar loads, L2-hot)
        const float* wrow = wbase + c * KC;
        float wcur[KC], wnxt[KC];
#pragma unroll
        for (int q = 0; q < KC; q += 4) {
            float4 v = *(const float4*)(wrow + q);
            wcur[q] = v.x; wcur[q+1] = v.y; wcur[q+2] = v.z; wcur[q+3] = v.w;
        }
#pragma unroll
        for (int j = 0; j < 16; ++j) {
            if (j < 15) {
#pragma unroll
                for (int q = 0; q < KC; q += 4) {
                    float4 v = *(const float4*)(wrow + (size_t)(j + 1) * HH + q);
                    wnxt[q] = v.x; wnxt[q+1] = v.y; wnxt[q+2] = v.z; wnxt[q+3] = v.w;
                }
            }
#pragma unroll
            for (int kk = 0; kk < KC; ++kk)
                acc[j] = fmaf(xr[kk], wcur[kk], acc[j]);
            if (j < 15) {
#pragma unroll
                for (int q = 0; q < KC; ++q) wcur[q] = wnxt[q];
            }
        }

        if (more) {
            float* d0 = &sx[buf ^ 1][srow * XS + scol];
            float* d1 = &sx[buf ^ 1][(srow + 32) * XS + scol];
            d0[0] = p0.x; d0[1] = p0.y; d0[2] = p0.z; d0[3] = p0.w;
            d1[0] = p1.x; d1[1] = p1.y; d1[2] = p1.z; d1[3] = p1.w;
        }
        __syncthreads();
    }

    // ---- write partials: P[s][tok0+l][e0..e0+16) : 4 float4 per lane ----
    float* Pp = P + ((size_t)s * NT + tok0 + l) * EE + e0;
#pragma unroll
    for (int q = 0; q < 16; q += 4) {
        float4 v;
        v.x = acc[q]; v.y = acc[q+1]; v.z = acc[q+2]; v.w = acc[q+3];
        *(float4*)(Pp + q) = v;
    }
}

// ---------------- Kernel 2: reduce S slices + logits + top-8 softmax ----------------
// grid 512, block 128. 32 tokens/WG; 4 threads per token for the reduction;
// lane-per-token top-k (numerics verbatim from rounds 3-5 — proven correct).
__global__ __launch_bounds__(128, 1) void reduce_topk(
    const float* __restrict__ P,   // [S][NT, E]
    int S,
    float* __restrict__ out_logits,
    float* __restrict__ out_wts,
    float* __restrict__ out_idx)
{
    __shared__ float slog[BT * LS];

    const int t    = threadIdx.x;
    const int tok0 = blockIdx.x * BT;
    const int tr   = t >> 2;        // token row 0..31
    const int p    = t & 3;         // expert 16-block

    float v[16];
#pragma unroll
    for (int c = 0; c < 4; ++c) {
        float4 a = *(const float4*)(P + ((size_t)(tok0 + tr)) * EE + 16 * p + 4 * c);
        v[4 * c + 0] = a.x; v[4 * c + 1] = a.y; v[4 * c + 2] = a.z; v[4 * c + 3] = a.w;
    }
    for (int s = 1; s < S; ++s) {
#pragma unroll
        for (int c = 0; c < 4; ++c) {
            float4 a = *(const float4*)(P + ((size_t)s * NT + tok0 + tr) * EE + 16 * p + 4 * c);
            v[4 * c + 0] += a.x; v[4 * c + 1] += a.y; v[4 * c + 2] += a.z; v[4 * c + 3] += a.w;
        }
    }

#pragma unroll
    for (int c = 0; c < 4; ++c) {
        float4 a;
        a.x = v[4 * c + 0]; a.y = v[4 * c + 1]; a.z = v[4 * c + 2]; a.w = v[4 * c + 3];
        *(float4*)(out_logits + (size_t)(tok0 + tr) * EE + 16 * p + 4 * c) = a;
        *(float4*)&slog[tr * LS + 16 * p + 4 * c] = a;
    }
    __syncthreads();

    if (t < BT) {
        float tv[TOPK];
        int   ti[TOPK];
#pragma unroll
        for (int q = 0; q < TOPK; ++q) { tv[q] = -INFINITY; ti[q] = 0; }

        for (int e = 0; e < EE; ++e) {
            const float val = slog[t * LS + e];
            if (val > tv[TOPK - 1]) {
                tv[TOPK - 1] = val;
                ti[TOPK - 1] = e;
#pragma unroll
                for (int q = TOPK - 1; q > 0; --q) {
                    if (tv[q] > tv[q - 1]) {   // strict: lowest-index-first on ties
                        float fv = tv[q]; tv[q] = tv[q - 1]; tv[q - 1] = fv;
                        int   fi = ti[q]; ti[q] = ti[q - 1]; ti[q - 1] = fi;
                    }
                }
            }
        }

        const float m = tv[0];
        float ew[TOPK];
        float sum = 0.f;
#pragma unroll
        for (int q = 0; q < TOPK; ++q) { ew[q] = expf(tv[q] - m); sum += ew[q]; }
        const float inv = 1.f / sum;

        const size_t tok = (size_t)(tok0 + t);
        float4 w0, w1, i0, i1;
        w0.x = ew[0] * inv; w0.y = ew[1] * inv; w0.z = ew[2] * inv; w0.w = ew[3] * inv;
        w1.x = ew[4] * inv; w1.y = ew[5] * inv; w1.z = ew[6] * inv; w1.w = ew[7] * inv;
        i0.x = (float)ti[0]; i0.y = (float)ti[1]; i0.z = (float)ti[2]; i0.w = (float)ti[3];
        i1.x = (float)ti[4]; i1.y = (float)ti[5]; i1.z = (float)ti[6]; i1.w = (float)ti[7];
        *(float4*)(out_wts + tok * TOPK)     = w0;
        *(float4*)(out_wts + tok * TOPK + 4) = w1;
        *(float4*)(out_idx + tok * TOPK)     = i0;
        *(float4*)(out_idx + tok * TOPK + 4) = i1;
    }
}

extern "C" void kernel_launch(void* const* d_in, const int* in_sizes, int n_in,
                              void* d_out, int out_size, void* d_ws, size_t ws_size,
                              hipStream_t stream) {
    const float* x = (const float*)d_in[0];   // hidden_states [4,4096,2048] fp32
    const float* w = (const float*)d_in[1];   // gate_w [64,2048] fp32
    float* out        = (float*)d_out;
    float* out_logits = out;                              // 16384*64
    float* out_wts    = out + (size_t)NT * EE;            // 16384*8
    float* out_idx    = out_wts + (size_t)NT * TOPK;      // 16384*8

    const size_t sliceB = (size_t)NT * EE * sizeof(float);   // 4.19 MB per slice
    int S;
    float* P;
    if (ws_size >= 4 * sliceB)      { S = 4; P = (float*)d_ws; }
    else if (ws_size >= 2 * sliceB) { S = 2; P = (float*)d_ws; }
    else                            { S = 1; P = out_logits; }

    dim3 grid1(NT / 64, S), block1(256);
    hipLaunchKernelGGL(gemm_xr, grid1, block1, 0, stream, x, w, P, HH / S);

    dim3 grid2(NT / BT), block2(128);
    hipLaunchKernelGGL(reduce_topk, grid2, block2, 0, stream,
                       P, S, out_logits, out_wts, out_idx);
}

// Round 7
// 422.132 us; speedup vs baseline: 1.3864x; 1.0139x over previous
//
#include <hip/hip_runtime.h>
#include <math.h>

// Problem constants
#define HH 2048
#define EE 64
#define TOPK 8
#define NT 16384
#define KC 32            // K per chunk
#define XS 33            // x LDS row stride (floats): banks (l+kk)%32 -> 2-way max (free)
#define BT 32            // tokens per WG in reduce kernel
#define LS 68            // slog row stride in reduce kernel

// ---------------- Kernel 1: fp32 GEMM partial, lane=token / wave=16 experts ----------------
// grid (256, S); block 256 = 4 waves. Token tile 64 (lane = token), wave wv owns
// experts wv*16..+16 (wave-uniform -> readfirstlane -> w loads go scalar, L2-hot).
// Per chunk: stage x[64][32] -> LDS (coalesced, double-buffered). Compute in 4
// groups of 8 k's: xr[8] regs loaded ONCE, then 16 experts x 8 FMAs reuse them.
// (Round 6 used xr[32] reused across the whole expert loop; the compiler demoted
// it to per-expert LDS re-reads — VGPR_Count 36 — making the kernel ds_read-bound
// at 283 us. The 8-float reuse window is too cheap to demote.)
// K ascending per accumulator (c up, g up, kk up) -> bitwise-identical partials
// to rounds 4/5/6.
__global__ __launch_bounds__(256, 1) void gemm_xr(
    const float* __restrict__ x,   // [NT, H]
    const float* __restrict__ w,   // [E, H]
    float* __restrict__ P,         // [S][NT, E]
    int kper)
{
    __shared__ float sx[2][64 * XS];

    const int t  = threadIdx.x;
    const int l  = t & 63;                    // lane = token within tile
    const int wv = t >> 6;                    // wave 0..3
    const int e0 = __builtin_amdgcn_readfirstlane(wv * 16);  // uniform expert base
    const int tok0 = blockIdx.x * 64;
    const int s    = blockIdx.y;
    const int k0   = s * kper;
    const int nch  = kper / KC;               // 16

    // staging: float4 index v = t and t+256; row = v>>3 (0..63), col = (v&7)*4
    const int srow = t >> 3;                  // 0..31 (second half via +32)
    const int scol = (t & 7) * 4;

    float acc[16];
#pragma unroll
    for (int j = 0; j < 16; ++j) acc[j] = 0.f;

    float4 p0, p1;

    // ---- prologue: chunk 0 ----
    p0 = *(const float4*)(x + (size_t)(tok0 + srow) * HH + k0 + scol);
    p1 = *(const float4*)(x + (size_t)(tok0 + srow + 32) * HH + k0 + scol);
    {
        float* d0 = &sx[0][srow * XS + scol];
        float* d1 = &sx[0][(srow + 32) * XS + scol];
        d0[0] = p0.x; d0[1] = p0.y; d0[2] = p0.z; d0[3] = p0.w;
        d1[0] = p1.x; d1[1] = p1.y; d1[2] = p1.z; d1[3] = p1.w;
    }
    __syncthreads();

    const float* wbase = w + (size_t)e0 * HH + k0;

    for (int c = 0; c < nch; ++c) {
        const int buf = c & 1;
        const bool more = (c + 1 < nch);
        if (more) {
            const int kn = k0 + (c + 1) * KC;
            p0 = *(const float4*)(x + (size_t)(tok0 + srow) * HH + kn + scol);
            p1 = *(const float4*)(x + (size_t)(tok0 + srow + 32) * HH + kn + scol);
        }

        const float* wrow = wbase + c * KC;

        // 4 groups of 8 k's: tiny register reuse window, immune to demotion
#pragma unroll
        for (int g = 0; g < 4; ++g) {
            float xr[8];
#pragma unroll
            for (int kk = 0; kk < 8; ++kk)
                xr[kk] = sx[buf][l * XS + g * 8 + kk];

#pragma unroll
            for (int j = 0; j < 16; ++j) {
                const float* wj = wrow + (size_t)j * HH + g * 8;   // uniform -> s_load
#pragma unroll
                for (int kk = 0; kk < 8; ++kk)
                    acc[j] = fmaf(xr[kk], wj[kk], acc[j]);
            }
        }

        if (more) {
            float* d0 = &sx[buf ^ 1][srow * XS + scol];
            float* d1 = &sx[buf ^ 1][(srow + 32) * XS + scol];
            d0[0] = p0.x; d0[1] = p0.y; d0[2] = p0.z; d0[3] = p0.w;
            d1[0] = p1.x; d1[1] = p1.y; d1[2] = p1.z; d1[3] = p1.w;
        }
        __syncthreads();
    }

    // ---- write partials: P[s][tok0+l][e0..e0+16) : 4 float4 per lane ----
    float* Pp = P + ((size_t)s * NT + tok0 + l) * EE + e0;
#pragma unroll
    for (int q = 0; q < 16; q += 4) {
        float4 v;
        v.x = acc[q]; v.y = acc[q+1]; v.z = acc[q+2]; v.w = acc[q+3];
        *(float4*)(Pp + q) = v;
    }
}

// ---------------- Kernel 2: reduce S slices + logits + top-8 softmax ----------------
// grid 512, block 128. 32 tokens/WG; 4 threads per token for the reduction;
// lane-per-token top-k (numerics verbatim from rounds 3-6 — proven correct).
__global__ __launch_bounds__(128, 1) void reduce_topk(
    const float* __restrict__ P,   // [S][NT, E]
    int S,
    float* __restrict__ out_logits,
    float* __restrict__ out_wts,
    float* __restrict__ out_idx)
{
    __shared__ float slog[BT * LS];

    const int t    = threadIdx.x;
    const int tok0 = blockIdx.x * BT;
    const int tr   = t >> 2;        // token row 0..31
    const int p    = t & 3;         // expert 16-block

    float v[16];
#pragma unroll
    for (int c = 0; c < 4; ++c) {
        float4 a = *(const float4*)(P + ((size_t)(tok0 + tr)) * EE + 16 * p + 4 * c);
        v[4 * c + 0] = a.x; v[4 * c + 1] = a.y; v[4 * c + 2] = a.z; v[4 * c + 3] = a.w;
    }
    for (int s = 1; s < S; ++s) {
#pragma unroll
        for (int c = 0; c < 4; ++c) {
            float4 a = *(const float4*)(P + ((size_t)s * NT + tok0 + tr) * EE + 16 * p + 4 * c);
            v[4 * c + 0] += a.x; v[4 * c + 1] += a.y; v[4 * c + 2] += a.z; v[4 * c + 3] += a.w;
        }
    }

#pragma unroll
    for (int c = 0; c < 4; ++c) {
        float4 a;
        a.x = v[4 * c + 0]; a.y = v[4 * c + 1]; a.z = v[4 * c + 2]; a.w = v[4 * c + 3];
        *(float4*)(out_logits + (size_t)(tok0 + tr) * EE + 16 * p + 4 * c) = a;
        *(float4*)&slog[tr * LS + 16 * p + 4 * c] = a;
    }
    __syncthreads();

    if (t < BT) {
        float tv[TOPK];
        int   ti[TOPK];
#pragma unroll
        for (int q = 0; q < TOPK; ++q) { tv[q] = -INFINITY; ti[q] = 0; }

        for (int e = 0; e < EE; ++e) {
            const float val = slog[t * LS + e];
            if (val > tv[TOPK - 1]) {
                tv[TOPK - 1] = val;
                ti[TOPK - 1] = e;
#pragma unroll
                for (int q = TOPK - 1; q > 0; --q) {
                    if (tv[q] > tv[q - 1]) {   // strict: lowest-index-first on ties
                        float fv = tv[q]; tv[q] = tv[q - 1]; tv[q - 1] = fv;
                        int   fi = ti[q]; ti[q] = ti[q - 1]; ti[q - 1] = fi;
                    }
                }
            }
        }

        const float m = tv[0];
        float ew[TOPK];
        float sum = 0.f;
#pragma unroll
        for (int q = 0; q < TOPK; ++q) { ew[q] = expf(tv[q] - m); sum += ew[q]; }
        const float inv = 1.f / sum;

        const size_t tok = (size_t)(tok0 + t);
        float4 w0, w1, i0, i1;
        w0.x = ew[0] * inv; w0.y = ew[1] * inv; w0.z = ew[2] * inv; w0.w = ew[3] * inv;
        w1.x = ew[4] * inv; w1.y = ew[5] * inv; w1.z = ew[6] * inv; w1.w = ew[7] * inv;
        i0.x = (float)ti[0]; i0.y = (float)ti[1]; i0.z = (float)ti[2]; i0.w = (float)ti[3];
        i1.x = (float)ti[4]; i1.y = (float)ti[5]; i1.z = (float)ti[6]; i1.w = (float)ti[7];
        *(float4*)(out_wts + tok * TOPK)     = w0;
        *(float4*)(out_wts + tok * TOPK + 4) = w1;
        *(float4*)(out_idx + tok * TOPK)     = i0;
        *(float4*)(out_idx + tok * TOPK + 4) = i1;
    }
}

extern "C" void kernel_launch(void* const* d_in, const int* in_sizes, int n_in,
                              void* d_out, int out_size, void* d_ws, size_t ws_size,
                              hipStream_t stream) {
    const float* x = (const float*)d_in[0];   // hidden_states [4,4096,2048] fp32
    const float* w = (const float*)d_in[1];   // gate_w [64,2048] fp32
    float* out        = (float*)d_out;
    float* out_logits = out;                              // 16384*64
    float* out_wts    = out + (size_t)NT * EE;            // 16384*8
    float* out_idx    = out_wts + (size_t)NT * TOPK;      // 16384*8

    const size_t sliceB = (size_t)NT * EE * sizeof(float);   // 4.19 MB per slice
    int S;
    float* P;
    if (ws_size >= 4 * sliceB)      { S = 4; P = (float*)d_ws; }
    else if (ws_size >= 2 * sliceB) { S = 2; P = (float*)d_ws; }
    else                            { S = 1; P = out_logits; }

    dim3 grid1(NT / 64, S), block1(256);
    hipLaunchKernelGGL(gemm_xr, grid1, block1, 0, stream, x, w, P, HH / S);

    dim3 grid2(NT / BT), block2(128);
    hipLaunchKernelGGL(reduce_topk, grid2, block2, 0, stream,
                       P, S, out_logits, out_wts, out_idx);
}